// Round 16
// baseline (248.074 us; speedup 1.0000x reference)
//
#include <hip/hip_runtime.h>
#include <hip/hip_fp16.h>

#define NEG_ATT 0.2f
#define BCAP 160000

// ---------------- setup: zero cnt + bucketCnt + wa = W @ a ----------------

__global__ __launch_bounds__(256) void setup_k(int* cnt, int N, int NB, int* bucketCnt,
                                               const float* __restrict__ W1, const float* __restrict__ a1s,
                                               const float* __restrict__ a1d, const float* __restrict__ W3,
                                               const float* __restrict__ a3s, const float* __restrict__ a3d,
                                               float* __restrict__ wa /* [4][64] */) {
    int b = blockIdx.x;
    if (b < NB) {
        int i = b * 256 + threadIdx.x;
        if (i < N) cnt[i] = 0;
    } else {
        int t = threadIdx.x;
        if (t < 8) bucketCnt[t] = 0;
        int ci = t & 63;
        int which = t >> 6;
        const float* W = (which < 2) ? W1 : W3;
        const float* a = (which == 0) ? a1s : (which == 1) ? a1d : (which == 2) ? a3s : a3d;
        float s = 0.f;
        for (int co = 0; co < 128; ++co) s += W[ci * 128 + co] * a[co];
        wa[t] = s;
    }
}

// ---------------- pass A: bin edges by dst range (read-once) + gemv + x16 ----------------
// Each edge read once; packed (dst<<16)|src appended to bucket p = dst/step via
// LDS histogram + one global atomicAdd per (block, bucket).

__global__ __launch_bounds__(256) void binA_gemv_k(const int* __restrict__ src, const int* __restrict__ dst,
                                                   unsigned* __restrict__ bucket, int* bucketCnt,
                                                   int E, int step, int AB,
                                                   const float* __restrict__ X,
                                                   const float* __restrict__ was, const float* __restrict__ wad,
                                                   float* __restrict__ as_, float* __restrict__ ad_,
                                                   __half* __restrict__ x16, int N) {
    if (blockIdx.x < AB) {
        __shared__ int lcnt[8];
        __shared__ int gbase[8];
        int tid = threadIdx.x;
        if (tid < 8) lcnt[tid] = 0;
        __syncthreads();
        int i4 = blockIdx.x * 256 + tid;
        int E4 = E >> 2;
        bool va = i4 < E4;
        int pp[4], loff[4];
        unsigned pk[4];
        if (va) {
            int4 d4 = *(const int4*)&dst[i4 * 4];
            int4 s4 = *(const int4*)&src[i4 * 4];
            int dd[4] = {d4.x, d4.y, d4.z, d4.w};
            int ss[4] = {s4.x, s4.y, s4.z, s4.w};
            #pragma unroll
            for (int u = 0; u < 4; ++u) {
                int p = dd[u] / step;
                pk[u] = ((unsigned)dd[u] << 16) | (unsigned)ss[u];
                pp[u] = p;
                loff[u] = atomicAdd(&lcnt[p], 1);
            }
        }
        __syncthreads();
        if (tid < 8) gbase[tid] = atomicAdd(&bucketCnt[tid], lcnt[tid]);
        __syncthreads();
        if (va) {
            #pragma unroll
            for (int u = 0; u < 4; ++u)
                bucket[pp[u] * BCAP + gbase[pp[u]] + loff[u]] = pk[u];
        }
        // tail (E % 4 != 0): direct global append
        if (blockIdx.x == 0 && tid < (E & 3)) {
            int i = (E & ~3) + tid;
            int dd = dst[i];
            int p = dd / step;
            int off = atomicAdd(&bucketCnt[p], 1);
            bucket[p * BCAP + off] = ((unsigned)dd << 16) | (unsigned)src[i];
        }
    } else {
        int wid  = ((blockIdx.x - AB) * 256 + threadIdx.x) >> 6;
        int lane = threadIdx.x & 63;
        if (wid >= N) return;
        float xv = X[(size_t)wid * 64 + lane];
        x16[(size_t)wid * 64 + lane] = __float2half(xv);
        float s1 = xv * was[lane];
        float s2 = xv * wad[lane];
        #pragma unroll
        for (int off = 32; off; off >>= 1) {
            s1 += __shfl_xor(s1, off);
            s2 += __shfl_xor(s2, off);
        }
        if (lane == 0) { as_[wid] = s1; ad_[wid] = s2; }
    }
}

// ---------------- pass B: XCD-local scatter from buckets ----------------
// Partition p = blockIdx&7: drains bucket p (contiguous reads); cnt/col
// lines for dst range p stay XCD-local.

__global__ __launch_bounds__(256) void binB_k(const unsigned* __restrict__ bucket, const int* __restrict__ bucketCnt,
                                              int* cnt, unsigned short* __restrict__ col, int GB) {
    int p = blockIdx.x & 7;
    int n = bucketCnt[p];
    int tg = (blockIdx.x >> 3) * 256 + threadIdx.x;
    int stride = (GB >> 3) * 256;
    for (int i = tg; i < n; i += stride) {
        unsigned e = bucket[p * BCAP + i];
        int dd = e >> 16;
        unsigned short ss = (unsigned short)(e & 0xffff);
        int slot = atomicAdd(&cnt[dd], 1);
        col[(dd << 6) + slot] = ss;
    }
}

// ---------------- wide GEMM: H16 = leaky(X16 @ W + b), CIN=64, COUT=128, fp16 in/out ----------------

__global__ __launch_bounds__(256) void gemm_wide_k(const __half* __restrict__ X16, const float* __restrict__ W,
                                                   const float* __restrict__ bias, __half* __restrict__ H16, int N) {
    __shared__ float Xs[128][68];
    __shared__ float Ws[64][128];
    int tid  = threadIdx.x;
    int row0 = blockIdx.x * 128;

    for (int i = tid; i < 2048; i += 256)
        *(float4*)&((float*)Ws)[i * 4] = *(const float4*)&W[i * 4];
    for (int i = tid; i < 2048; i += 256) {
        int r = i >> 4, k4 = i & 15;
        int gr = row0 + r;
        float4 v = {0.f, 0.f, 0.f, 0.f};
        if (gr < N) {
            uint2 pk = *(const uint2*)&X16[(size_t)gr * 64 + k4 * 4];
            float2 f0 = __half22float2(*(__half2*)&pk.x);
            float2 f1 = __half22float2(*(__half2*)&pk.y);
            v = make_float4(f0.x, f0.y, f1.x, f1.y);
        }
        *(float4*)&Xs[r][k4 * 4] = v;
    }
    __syncthreads();

    int ct = tid & 15;
    int rt = tid >> 4;
    float acc[8][8] = {};
    for (int k = 0; k < 64; k += 4) {
        float4 w0a = *(float4*)&Ws[k][ct * 8],     w0b = *(float4*)&Ws[k][ct * 8 + 4];
        float4 w1a = *(float4*)&Ws[k + 1][ct * 8], w1b = *(float4*)&Ws[k + 1][ct * 8 + 4];
        float4 w2a = *(float4*)&Ws[k + 2][ct * 8], w2b = *(float4*)&Ws[k + 2][ct * 8 + 4];
        float4 w3a = *(float4*)&Ws[k + 3][ct * 8], w3b = *(float4*)&Ws[k + 3][ct * 8 + 4];
        #pragma unroll
        for (int i = 0; i < 8; ++i) {
            float4 xv = *(float4*)&Xs[rt + 16 * i][k];
            acc[i][0] += xv.x * w0a.x + xv.y * w1a.x + xv.z * w2a.x + xv.w * w3a.x;
            acc[i][1] += xv.x * w0a.y + xv.y * w1a.y + xv.z * w2a.y + xv.w * w3a.y;
            acc[i][2] += xv.x * w0a.z + xv.y * w1a.z + xv.z * w2a.z + xv.w * w3a.z;
            acc[i][3] += xv.x * w0a.w + xv.y * w1a.w + xv.z * w2a.w + xv.w * w3a.w;
            acc[i][4] += xv.x * w0b.x + xv.y * w1b.x + xv.z * w2b.x + xv.w * w3b.x;
            acc[i][5] += xv.x * w0b.y + xv.y * w1b.y + xv.z * w2b.y + xv.w * w3b.y;
            acc[i][6] += xv.x * w0b.z + xv.y * w1b.z + xv.z * w2b.z + xv.w * w3b.z;
            acc[i][7] += xv.x * w0b.w + xv.y * w1b.w + xv.z * w2b.w + xv.w * w3b.w;
        }
    }

    float bv[8];
    #pragma unroll
    for (int j = 0; j < 8; ++j) bv[j] = bias[ct * 8 + j];

    #pragma unroll
    for (int i = 0; i < 8; ++i) {
        int gr = row0 + rt + 16 * i;
        if (gr < N) {
            float o[8];
            #pragma unroll
            for (int j = 0; j < 8; ++j) {
                float v = acc[i][j] + bv[j];
                o[j] = v > 0.f ? v : 0.01f * v;
            }
            __half2 h0 = __floats2half2_rn(o[0], o[1]);
            __half2 h1 = __floats2half2_rn(o[2], o[3]);
            __half2 h2 = __floats2half2_rn(o[4], o[5]);
            __half2 h3 = __floats2half2_rn(o[6], o[7]);
            uint4 pk = { *(unsigned*)&h0, *(unsigned*)&h1, *(unsigned*)&h2, *(unsigned*)&h3 };
            *(uint4*)&H16[(size_t)gr * 128 + ct * 8] = pk;
        }
    }
}

// ---------------- GEMM: H(fp16) = X16 @ W, CIN=128; + att logits ----------------

template <int CIN, int COUT>
__global__ __launch_bounds__(256) void gemm_k(const __half* __restrict__ X16, const float* __restrict__ W,
                                              const float* __restrict__ a_s, const float* __restrict__ a_d,
                                              __half* __restrict__ Hh, float* __restrict__ as_,
                                              float* __restrict__ ad_, int N) {
    constexpr int RB  = (CIN == 128 && COUT == 64) ? 32 : 64;
    constexpr int NCT = COUT / 4;
    constexpr int NRT = 256 / NCT;
    constexpr int RT  = RB / NRT;
    constexpr int XP  = CIN + 4;
    __shared__ float Xs[RB][XP];
    __shared__ float Ws[CIN][COUT];
    int tid  = threadIdx.x;
    int row0 = blockIdx.x * RB;

    for (int i = tid; i < CIN * COUT / 4; i += 256)
        *(float4*)&((float*)Ws)[i * 4] = *(const float4*)&W[i * 4];
    for (int i = tid; i < RB * CIN / 4; i += 256) {
        int r = i / (CIN / 4), k4 = i % (CIN / 4);
        int gr = row0 + r;
        float4 v = {0.f, 0.f, 0.f, 0.f};
        if (gr < N) {
            uint2 pk = *(const uint2*)&X16[(size_t)gr * CIN + k4 * 4];
            float2 f0 = __half22float2(*(__half2*)&pk.x);
            float2 f1 = __half22float2(*(__half2*)&pk.y);
            v = make_float4(f0.x, f0.y, f1.x, f1.y);
        }
        *(float4*)&Xs[r][k4 * 4] = v;
    }
    __syncthreads();

    int ct = tid % NCT;
    int rt = tid / NCT;
    float acc[RT][4] = {};
    for (int k = 0; k < CIN; k += 4) {
        float4 w0 = *(float4*)&Ws[k][ct * 4];
        float4 w1 = *(float4*)&Ws[k + 1][ct * 4];
        float4 w2 = *(float4*)&Ws[k + 2][ct * 4];
        float4 w3 = *(float4*)&Ws[k + 3][ct * 4];
        #pragma unroll
        for (int i = 0; i < RT; ++i) {
            float4 xv = *(float4*)&Xs[rt + i * NRT][k];
            acc[i][0] += xv.x * w0.x + xv.y * w1.x + xv.z * w2.x + xv.w * w3.x;
            acc[i][1] += xv.x * w0.y + xv.y * w1.y + xv.z * w2.y + xv.w * w3.y;
            acc[i][2] += xv.x * w0.z + xv.y * w1.z + xv.z * w2.z + xv.w * w3.z;
            acc[i][3] += xv.x * w0.w + xv.y * w1.w + xv.z * w2.w + xv.w * w3.w;
        }
    }

    float asv[4], adv[4];
    #pragma unroll
    for (int j = 0; j < 4; ++j) { asv[j] = a_s[ct * 4 + j]; adv[j] = a_d[ct * 4 + j]; }

    #pragma unroll
    for (int i = 0; i < RT; ++i) {
        int gr = row0 + rt + i * NRT;
        float s1 = acc[i][0] * asv[0] + acc[i][1] * asv[1] + acc[i][2] * asv[2] + acc[i][3] * asv[3];
        float s2 = acc[i][0] * adv[0] + acc[i][1] * adv[1] + acc[i][2] * adv[2] + acc[i][3] * adv[3];
        #pragma unroll
        for (int off = 1; off < NCT; off <<= 1) {
            s1 += __shfl_xor(s1, off);
            s2 += __shfl_xor(s2, off);
        }
        if (gr < N) {
            __half2 p0 = __floats2half2_rn(acc[i][0], acc[i][1]);
            __half2 p1 = __floats2half2_rn(acc[i][2], acc[i][3]);
            uint2 pk = { *(unsigned*)&p0, *(unsigned*)&p1 };
            *(uint2*)&Hh[(size_t)gr * COUT + ct * 4] = pk;
            if (ct == 0) { as_[gr] = s1; ad_[gr] = s2; }
        }
    }
}

// ---------------- aggregate (padded CSR, fp16, half2 paired gathers, dg-dispatch) ----------------
// MODE 0: weighted mean -> fp16 out (C=64)
// MODE 1: +bias +leaky +fused GEMV logits -> fp16 out (C=64)
// MODE 2: +bias -> fp32 out (C=32, final)

template <int C, int MODE>
__global__ __launch_bounds__(256) void agg_k(const __half* __restrict__ Hg, const float* __restrict__ as_,
                                             const float* __restrict__ ad_, const int* __restrict__ deg,
                                             const unsigned short* __restrict__ col, const float* __restrict__ bias,
                                             const float* __restrict__ was, const float* __restrict__ wad,
                                             float* __restrict__ outf, __half* __restrict__ outh,
                                             float* __restrict__ oas, float* __restrict__ oad, int N) {
    __shared__ int2 sw[4][64];
    int wid  = (blockIdx.x * 256 + threadIdx.x) >> 6;
    int lane = threadIdx.x & 63;
    int wvi  = threadIdx.x >> 6;
    if (wid >= N) return;
    float adi = ad_[wid];
    int dg = deg[wid];
    float a0 = 0.f, a1 = 0.f, b0 = 0.f, b1 = 0.f;
    const int sub  = lane >> 5, c32 = lane & 31;
    const int quad = lane >> 4, c16 = lane & 15;

    int s_l = 0; float w_l = 0.f;
    if (lane < dg) {
        s_l = col[(wid << 6) + lane];
        float e = as_[s_l] + adi;
        e = e > 0.f ? e : NEG_ATT * e;
        w_l = __expf(e);
    }
    sw[wvi][lane] = make_int2(s_l, __float_as_int(w_l));

    // self-loop (added once: sub==0 / quad==0)
    float es = as_[wid] + adi;
    es = es > 0.f ? es : NEG_ATT * es;
    float ws = __expf(es);
    float denom = w_l + ((lane == 0) ? ws : 0.f);
    if (C == 64) {
        if (!sub) {
            float2 f = __half22float2(*(const __half2*)&Hg[((size_t)wid << 6) + 2 * c32]);
            a0 += ws * f.x; a1 += ws * f.y;
        }
    } else {
        if (!quad) {
            float2 f = __half22float2(*(const __half2*)&Hg[((size_t)wid << 5) + 2 * c16]);
            a0 += ws * f.x; a1 += ws * f.y;
        }
    }

    auto g64 = [&](int j, auto NEhalf) {  // M loads/lane, 2M edges
        constexpr int M = decltype(NEhalf)::value;
        float2 hv[M]; float wv[M];
        #pragma unroll
        for (int u = 0; u < M; ++u) {
            int2 p = sw[wvi][j + 2 * u + sub];
            wv[u] = __int_as_float(p.y);
            hv[u] = __half22float2(*(const __half2*)&Hg[((size_t)p.x << 6) + 2 * c32]);
        }
        #pragma unroll
        for (int u = 0; u < M; ++u) {
            if (u & 1) { b0 += wv[u] * hv[u].x; b1 += wv[u] * hv[u].y; }
            else       { a0 += wv[u] * hv[u].x; a1 += wv[u] * hv[u].y; }
        }
    };
    auto g32 = [&](int j, auto NEq) {  // M loads/lane, 4M edges
        constexpr int M = decltype(NEq)::value;
        float2 hv[M]; float wv[M];
        #pragma unroll
        for (int u = 0; u < M; ++u) {
            int2 p = sw[wvi][j + 4 * u + quad];
            wv[u] = __int_as_float(p.y);
            hv[u] = __half22float2(*(const __half2*)&Hg[((size_t)p.x << 5) + 2 * c16]);
        }
        #pragma unroll
        for (int u = 0; u < M; ++u) {
            if (u & 1) { b0 += wv[u] * hv[u].x; b1 += wv[u] * hv[u].y; }
            else       { a0 += wv[u] * hv[u].x; a1 += wv[u] * hv[u].y; }
        }
    };

    if (C == 64) {
        if (dg <= 8)       g64(0, std::integral_constant<int, 4>{});
        else if (dg <= 16) g64(0, std::integral_constant<int, 8>{});
        else if (dg <= 32) g64(0, std::integral_constant<int, 16>{});
        else { g64(0, std::integral_constant<int, 16>{}); g64(32, std::integral_constant<int, 16>{}); }
    } else {
        if (dg <= 16)      g32(0, std::integral_constant<int, 4>{});
        else if (dg <= 32) g32(0, std::integral_constant<int, 8>{});
        else { g32(0, std::integral_constant<int, 8>{}); g32(32, std::integral_constant<int, 8>{}); }
    }

    float f0 = a0 + b0, f1 = a1 + b1;
    if (C == 32) { f0 += __shfl_xor(f0, 16); f1 += __shfl_xor(f1, 16); }
    f0 += __shfl_xor(f0, 32); f1 += __shfl_xor(f1, 32);
    #pragma unroll
    for (int off = 32; off; off >>= 1) denom += __shfl_xor(denom, off);

    float inv = 1.f / denom;
    float v0 = f0 * inv, v1 = f1 * inv;

    if (MODE == 0) {
        if (!sub) {
            __half2 p = __floats2half2_rn(v0, v1);
            *(__half2*)&outh[((size_t)wid << 6) + 2 * c32] = p;
        }
    } else if (MODE == 1) {
        float2 bb = *(const float2*)&bias[2 * c32];
        v0 += bb.x; v1 += bb.y;
        v0 = v0 > 0.f ? v0 : 0.01f * v0;
        v1 = v1 > 0.f ? v1 : 0.01f * v1;
        if (!sub) {
            __half2 p = __floats2half2_rn(v0, v1);
            *(__half2*)&outh[((size_t)wid << 6) + 2 * c32] = p;
        }
        float2 wsv = *(const float2*)&was[2 * c32];
        float2 wdv = *(const float2*)&wad[2 * c32];
        float s1 = v0 * wsv.x + v1 * wsv.y;
        float s2 = v0 * wdv.x + v1 * wdv.y;
        #pragma unroll
        for (int off = 16; off; off >>= 1) {
            s1 += __shfl_xor(s1, off);
            s2 += __shfl_xor(s2, off);
        }
        if (lane == 0) { oas[wid] = s1; oad[wid] = s2; }
    } else {
        if (!quad) {
            float2 bb = *(const float2*)&bias[2 * c16];
            float2 o = {v0 + bb.x, v1 + bb.y};
            *(float2*)&outf[((size_t)wid << 5) + 2 * c16] = o;
        }
    }
}

// ---------------- launch ----------------

extern "C" void kernel_launch(void* const* d_in, const int* in_sizes, int n_in,
                              void* d_out, int out_size, void* d_ws, size_t ws_size,
                              hipStream_t stream) {
    const float* x  = (const float*)d_in[0];
    const int* ei   = (const int*)d_in[1];
    const float* W1 = (const float*)d_in[2];
    const float* a1s = (const float*)d_in[3];
    const float* a1d = (const float*)d_in[4];
    const float* b1  = (const float*)d_in[5];
    const float* W2 = (const float*)d_in[6];
    const float* a2s = (const float*)d_in[7];
    const float* a2d = (const float*)d_in[8];
    const float* b2  = (const float*)d_in[9];
    const float* W3 = (const float*)d_in[10];
    const float* a3s = (const float*)d_in[11];
    const float* a3d = (const float*)d_in[12];
    const float* b3  = (const float*)d_in[13];
    const float* W4 = (const float*)d_in[14];
    const float* a4s = (const float*)d_in[15];
    const float* a4d = (const float*)d_in[16];
    const float* b4  = (const float*)d_in[17];

    const int N = in_sizes[0] / 64;     // 50000
    const int E = in_sizes[1] / 2;      // 800000
    const int* src = ei;
    const int* dst = ei + E;

    // workspace layout
    float* asA  = (float*)d_ws;             // N
    float* adA  = asA + N;                  // N
    float* asB  = adA + N;                  // N
    float* adB  = asB + N;                  // N
    float* wa   = adB + N;                  // 256 (4x64)
    int* bucketCnt = (int*)(wa + 256);      // 8 (+ pad to 16B)
    int* cnt    = bucketCnt + 16;           // N (degree after scatter)
    unsigned short* col = (unsigned short*)(cnt + N);  // N*64 ushort padded CSR
    unsigned* bucket = (unsigned*)(col + (size_t)N * 64);  // 8*BCAP u32
    __half* x16 = (__half*)(bucket + 8 * (size_t)BCAP);    // N*64 fp16
    __half* g1  = x16 + (size_t)N * 64;     // N*64 fp16 (H2 / H4)
    __half* g2  = g1 + (size_t)N * 64;      // N*64 fp16 (O2)
    __half* g3  = g2 + (size_t)N * 64;      // N*64 fp16 (T1/T3)
    __half* g4  = g3 + (size_t)N * 64;      // N*128 fp16 (H1/H3)

    const int NB = (N + 255) / 256;         // 196
    const int STEP = (N + 7) / 8;           // 6250
    const int AB = ((E >> 2) + 255) / 256;  // 782 binning blocks
    const int GB = 2048;                    // pass-B blocks
    const int NWAVE = (N * 64 + 255) / 256; // 12500

    // ---- setup: zero cnt + bucketCnt + wa vectors ----
    setup_k<<<NB + 1, 256, 0, stream>>>(cnt, N, NB, bucketCnt, W1, a1s, a1d, W3, a3s, a3d, wa);
    float* wa1s = wa, *wa1d = wa + 64, *wa3s = wa + 128, *wa3d = wa + 192;

    // ---- pass A: bin edges (read-once) + layer-1 gemv + x16 ----
    binA_gemv_k<<<AB + NWAVE, 256, 0, stream>>>(src, dst, bucket, bucketCnt, E, STEP, AB,
                                                x, wa1s, wa1d, asA, adA, x16, N);

    // ---- pass B: XCD-local scatter from buckets ----
    binB_k<<<GB, 256, 0, stream>>>(bucket, bucketCnt, cnt, col, GB);

    // ---- layer 1 (aggregate-first): T1(fp16) = Ahat @ x ; H1(fp16) = leaky(T1@W1 + b1) ----
    agg_k<64, 0><<<NWAVE, 256, 0, stream>>>(x16, asA, adA, cnt, col, nullptr, nullptr, nullptr,
                                            nullptr, g3, nullptr, nullptr, N);
    gemm_wide_k<<<(N + 127) / 128, 256, 0, stream>>>(g3, W1, b1, g4, N);

    // ---- layer 2: H2(fp16) = H1 @ W2 (+logits2) ; O2(fp16) = leaky(Ahat@H2+b2) (+logits3) ----
    gemm_k<128, 64><<<(N + 31) / 32, 256, 0, stream>>>(g4, W2, a2s, a2d, g1, asB, adB, N);
    agg_k<64, 1><<<NWAVE, 256, 0, stream>>>(g1, asB, adB, cnt, col, b2, wa3s, wa3d,
                                            nullptr, g2, asA, adA, N);

    // ---- layer 3 (aggregate-first): T3(fp16) = Ahat @ O2 ; H3(fp16) = leaky(T3@W3 + b3) ----
    agg_k<64, 0><<<NWAVE, 256, 0, stream>>>(g2, asA, adA, cnt, col, nullptr, nullptr, nullptr,
                                            nullptr, g3, nullptr, nullptr, N);
    gemm_wide_k<<<(N + 127) / 128, 256, 0, stream>>>(g3, W3, b3, g4, N);

    // ---- layer 4: H4(fp16) = H3 @ W4 (+logits4) ; out = Ahat@H4 + b4 ----
    gemm_k<128, 32><<<(N + 63) / 64, 256, 0, stream>>>(g4, W4, a4s, a4d, g1, asB, adB, N);
    agg_k<32, 2><<<NWAVE, 256, 0, stream>>>(g1, asB, adB, cnt, col, b4, nullptr, nullptr,
                                            (float*)d_out, nullptr, nullptr, nullptr, N);
}

// Round 17
// 243.638 us; speedup vs baseline: 1.0182x; 1.0182x over previous
//
#include <hip/hip_runtime.h>
#include <hip/hip_fp16.h>

#define NEG_ATT 0.2f

// ---------------- setup: zero cnt + wa = W @ a ----------------

__global__ __launch_bounds__(256) void setup_k(int* cnt, int N, int NB,
                                               const float* __restrict__ W1, const float* __restrict__ a1s,
                                               const float* __restrict__ a1d, const float* __restrict__ W3,
                                               const float* __restrict__ a3s, const float* __restrict__ a3d,
                                               float* __restrict__ wa /* [4][64] */) {
    int b = blockIdx.x;
    if (b < NB) {
        int i = b * 256 + threadIdx.x;
        if (i < N) cnt[i] = 0;
    } else {
        int t = threadIdx.x;
        int ci = t & 63;
        int which = t >> 6;
        const float* W = (which < 2) ? W1 : W3;
        const float* a = (which == 0) ? a1s : (which == 1) ? a1d : (which == 2) ? a3s : a3d;
        float s = 0.f;
        for (int co = 0; co < 128; ++co) s += W[ci * 128 + co] * a[co];
        wa[t] = s;
    }
}

// ---------------- padded-CSR scatter (dst-partition == XCD) + gemv + x16 ----------------
// Partition p = blockIdx&7 handles dst range [p*step,(p+1)*step): all atomics
// and col writes stay XCD-local (proven fastest across r11-r16 experiments).

__global__ __launch_bounds__(256) void scatter_gemv_k(const int* __restrict__ src, const int* __restrict__ dst,
                                                      int* cnt, unsigned short* __restrict__ col,
                                                      int E, int step, int SB, int iters4,
                                                      const float* __restrict__ X,
                                                      const float* __restrict__ was, const float* __restrict__ wad,
                                                      float* __restrict__ as_, float* __restrict__ ad_,
                                                      __half* __restrict__ x16, int N) {
    if (blockIdx.x < SB) {
        int part = blockIdx.x & 7;
        int lo = part * step, hi = lo + step;
        int tg = (blockIdx.x >> 3) * 256 + threadIdx.x;
        int stride = (SB >> 3) * 256;
        const int4* dst4 = (const int4*)dst;
        int E4 = E >> 2;
        for (int it = 0; it < iters4; ++it) {
            int i4 = tg + it * stride;
            if (i4 < E4) {
                int4 d4 = dst4[i4];
                int base = i4 << 2;
                if (d4.x >= lo && d4.x < hi) { int s = atomicAdd(&cnt[d4.x], 1); col[(d4.x << 6) + s] = (unsigned short)src[base]; }
                if (d4.y >= lo && d4.y < hi) { int s = atomicAdd(&cnt[d4.y], 1); col[(d4.y << 6) + s] = (unsigned short)src[base + 1]; }
                if (d4.z >= lo && d4.z < hi) { int s = atomicAdd(&cnt[d4.z], 1); col[(d4.z << 6) + s] = (unsigned short)src[base + 2]; }
                if (d4.w >= lo && d4.w < hi) { int s = atomicAdd(&cnt[d4.w], 1); col[(d4.w << 6) + s] = (unsigned short)src[base + 3]; }
            }
        }
        // scalar tail (E % 4 != 0)
        for (int i = (E & ~3) + tg; i < E; i += stride) {
            int dd = dst[i];
            if (dd >= lo && dd < hi) { int s = atomicAdd(&cnt[dd], 1); col[(dd << 6) + s] = (unsigned short)src[i]; }
        }
    } else {
        int wid  = ((blockIdx.x - SB) * 256 + threadIdx.x) >> 6;
        int lane = threadIdx.x & 63;
        if (wid >= N) return;
        float xv = X[(size_t)wid * 64 + lane];
        x16[(size_t)wid * 64 + lane] = __float2half(xv);
        float s1 = xv * was[lane];
        float s2 = xv * wad[lane];
        #pragma unroll
        for (int off = 32; off; off >>= 1) {
            s1 += __shfl_xor(s1, off);
            s2 += __shfl_xor(s2, off);
        }
        if (lane == 0) { as_[wid] = s1; ad_[wid] = s2; }
    }
}

// ---------------- wide GEMM: H16 = leaky(X16 @ W + b), CIN=64, COUT=128, fp16 in/out ----------------

__global__ __launch_bounds__(256) void gemm_wide_k(const __half* __restrict__ X16, const float* __restrict__ W,
                                                   const float* __restrict__ bias, __half* __restrict__ H16, int N) {
    __shared__ float Xs[128][68];
    __shared__ float Ws[64][128];
    int tid  = threadIdx.x;
    int row0 = blockIdx.x * 128;

    for (int i = tid; i < 2048; i += 256)
        *(float4*)&((float*)Ws)[i * 4] = *(const float4*)&W[i * 4];
    for (int i = tid; i < 2048; i += 256) {
        int r = i >> 4, k4 = i & 15;
        int gr = row0 + r;
        float4 v = {0.f, 0.f, 0.f, 0.f};
        if (gr < N) {
            uint2 pk = *(const uint2*)&X16[(size_t)gr * 64 + k4 * 4];
            float2 f0 = __half22float2(*(__half2*)&pk.x);
            float2 f1 = __half22float2(*(__half2*)&pk.y);
            v = make_float4(f0.x, f0.y, f1.x, f1.y);
        }
        *(float4*)&Xs[r][k4 * 4] = v;
    }
    __syncthreads();

    int ct = tid & 15;
    int rt = tid >> 4;
    float acc[8][8] = {};
    for (int k = 0; k < 64; k += 4) {
        float4 w0a = *(float4*)&Ws[k][ct * 8],     w0b = *(float4*)&Ws[k][ct * 8 + 4];
        float4 w1a = *(float4*)&Ws[k + 1][ct * 8], w1b = *(float4*)&Ws[k + 1][ct * 8 + 4];
        float4 w2a = *(float4*)&Ws[k + 2][ct * 8], w2b = *(float4*)&Ws[k + 2][ct * 8 + 4];
        float4 w3a = *(float4*)&Ws[k + 3][ct * 8], w3b = *(float4*)&Ws[k + 3][ct * 8 + 4];
        #pragma unroll
        for (int i = 0; i < 8; ++i) {
            float4 xv = *(float4*)&Xs[rt + 16 * i][k];
            acc[i][0] += xv.x * w0a.x + xv.y * w1a.x + xv.z * w2a.x + xv.w * w3a.x;
            acc[i][1] += xv.x * w0a.y + xv.y * w1a.y + xv.z * w2a.y + xv.w * w3a.y;
            acc[i][2] += xv.x * w0a.z + xv.y * w1a.z + xv.z * w2a.z + xv.w * w3a.z;
            acc[i][3] += xv.x * w0a.w + xv.y * w1a.w + xv.z * w2a.w + xv.w * w3a.w;
            acc[i][4] += xv.x * w0b.x + xv.y * w1b.x + xv.z * w2b.x + xv.w * w3b.x;
            acc[i][5] += xv.x * w0b.y + xv.y * w1b.y + xv.z * w2b.y + xv.w * w3b.y;
            acc[i][6] += xv.x * w0b.z + xv.y * w1b.z + xv.z * w2b.z + xv.w * w3b.z;
            acc[i][7] += xv.x * w0b.w + xv.y * w1b.w + xv.z * w2b.w + xv.w * w3b.w;
        }
    }

    float bv[8];
    #pragma unroll
    for (int j = 0; j < 8; ++j) bv[j] = bias[ct * 8 + j];

    #pragma unroll
    for (int i = 0; i < 8; ++i) {
        int gr = row0 + rt + 16 * i;
        if (gr < N) {
            float o[8];
            #pragma unroll
            for (int j = 0; j < 8; ++j) {
                float v = acc[i][j] + bv[j];
                o[j] = v > 0.f ? v : 0.01f * v;
            }
            __half2 h0 = __floats2half2_rn(o[0], o[1]);
            __half2 h1 = __floats2half2_rn(o[2], o[3]);
            __half2 h2 = __floats2half2_rn(o[4], o[5]);
            __half2 h3 = __floats2half2_rn(o[6], o[7]);
            uint4 pk = { *(unsigned*)&h0, *(unsigned*)&h1, *(unsigned*)&h2, *(unsigned*)&h3 };
            *(uint4*)&H16[(size_t)gr * 128 + ct * 8] = pk;
        }
    }
}

// ---------------- GEMM: H(fp16) = X16 @ W, CIN=128; + att logits ----------------

template <int CIN, int COUT>
__global__ __launch_bounds__(256) void gemm_k(const __half* __restrict__ X16, const float* __restrict__ W,
                                              const float* __restrict__ a_s, const float* __restrict__ a_d,
                                              __half* __restrict__ Hh, float* __restrict__ as_,
                                              float* __restrict__ ad_, int N) {
    constexpr int RB  = (CIN == 128 && COUT == 64) ? 32 : 64;
    constexpr int NCT = COUT / 4;
    constexpr int NRT = 256 / NCT;
    constexpr int RT  = RB / NRT;
    constexpr int XP  = CIN + 4;
    __shared__ float Xs[RB][XP];
    __shared__ float Ws[CIN][COUT];
    int tid  = threadIdx.x;
    int row0 = blockIdx.x * RB;

    for (int i = tid; i < CIN * COUT / 4; i += 256)
        *(float4*)&((float*)Ws)[i * 4] = *(const float4*)&W[i * 4];
    for (int i = tid; i < RB * CIN / 4; i += 256) {
        int r = i / (CIN / 4), k4 = i % (CIN / 4);
        int gr = row0 + r;
        float4 v = {0.f, 0.f, 0.f, 0.f};
        if (gr < N) {
            uint2 pk = *(const uint2*)&X16[(size_t)gr * CIN + k4 * 4];
            float2 f0 = __half22float2(*(__half2*)&pk.x);
            float2 f1 = __half22float2(*(__half2*)&pk.y);
            v = make_float4(f0.x, f0.y, f1.x, f1.y);
        }
        *(float4*)&Xs[r][k4 * 4] = v;
    }
    __syncthreads();

    int ct = tid % NCT;
    int rt = tid / NCT;
    float acc[RT][4] = {};
    for (int k = 0; k < CIN; k += 4) {
        float4 w0 = *(float4*)&Ws[k][ct * 4];
        float4 w1 = *(float4*)&Ws[k + 1][ct * 4];
        float4 w2 = *(float4*)&Ws[k + 2][ct * 4];
        float4 w3 = *(float4*)&Ws[k + 3][ct * 4];
        #pragma unroll
        for (int i = 0; i < RT; ++i) {
            float4 xv = *(float4*)&Xs[rt + i * NRT][k];
            acc[i][0] += xv.x * w0.x + xv.y * w1.x + xv.z * w2.x + xv.w * w3.x;
            acc[i][1] += xv.x * w0.y + xv.y * w1.y + xv.z * w2.y + xv.w * w3.y;
            acc[i][2] += xv.x * w0.z + xv.y * w1.z + xv.z * w2.z + xv.w * w3.z;
            acc[i][3] += xv.x * w0.w + xv.y * w1.w + xv.z * w2.w + xv.w * w3.w;
        }
    }

    float asv[4], adv[4];
    #pragma unroll
    for (int j = 0; j < 4; ++j) { asv[j] = a_s[ct * 4 + j]; adv[j] = a_d[ct * 4 + j]; }

    #pragma unroll
    for (int i = 0; i < RT; ++i) {
        int gr = row0 + rt + i * NRT;
        float s1 = acc[i][0] * asv[0] + acc[i][1] * asv[1] + acc[i][2] * asv[2] + acc[i][3] * asv[3];
        float s2 = acc[i][0] * adv[0] + acc[i][1] * adv[1] + acc[i][2] * adv[2] + acc[i][3] * adv[3];
        #pragma unroll
        for (int off = 1; off < NCT; off <<= 1) {
            s1 += __shfl_xor(s1, off);
            s2 += __shfl_xor(s2, off);
        }
        if (gr < N) {
            __half2 p0 = __floats2half2_rn(acc[i][0], acc[i][1]);
            __half2 p1 = __floats2half2_rn(acc[i][2], acc[i][3]);
            uint2 pk = { *(unsigned*)&p0, *(unsigned*)&p1 };
            *(uint2*)&Hh[(size_t)gr * COUT + ct * 4] = pk;
            if (ct == 0) { as_[gr] = s1; ad_[gr] = s2; }
        }
    }
}

// ---------------- aggregate (padded CSR, fp16, half2 paired gathers, dg-dispatch) ----------------
// MODE 0: weighted mean -> fp16 out (C=64)
// MODE 1: +bias +leaky +fused GEMV logits -> fp16 out (C=64)
// MODE 2: +bias -> fp32 out (C=32, final)

template <int C, int MODE>
__global__ __launch_bounds__(256) void agg_k(const __half* __restrict__ Hg, const float* __restrict__ as_,
                                             const float* __restrict__ ad_, const int* __restrict__ deg,
                                             const unsigned short* __restrict__ col, const float* __restrict__ bias,
                                             const float* __restrict__ was, const float* __restrict__ wad,
                                             float* __restrict__ outf, __half* __restrict__ outh,
                                             float* __restrict__ oas, float* __restrict__ oad, int N) {
    __shared__ int2 sw[4][64];
    int wid  = (blockIdx.x * 256 + threadIdx.x) >> 6;
    int lane = threadIdx.x & 63;
    int wvi  = threadIdx.x >> 6;
    if (wid >= N) return;
    float adi = ad_[wid];
    int dg = deg[wid];
    float a0 = 0.f, a1 = 0.f, b0 = 0.f, b1 = 0.f;
    const int sub  = lane >> 5, c32 = lane & 31;
    const int quad = lane >> 4, c16 = lane & 15;

    int s_l = 0; float w_l = 0.f;
    if (lane < dg) {
        s_l = col[(wid << 6) + lane];
        float e = as_[s_l] + adi;
        e = e > 0.f ? e : NEG_ATT * e;
        w_l = __expf(e);
    }
    sw[wvi][lane] = make_int2(s_l, __float_as_int(w_l));

    // self-loop (added once: sub==0 / quad==0)
    float es = as_[wid] + adi;
    es = es > 0.f ? es : NEG_ATT * es;
    float ws = __expf(es);
    float denom = w_l + ((lane == 0) ? ws : 0.f);
    if (C == 64) {
        if (!sub) {
            float2 f = __half22float2(*(const __half2*)&Hg[((size_t)wid << 6) + 2 * c32]);
            a0 += ws * f.x; a1 += ws * f.y;
        }
    } else {
        if (!quad) {
            float2 f = __half22float2(*(const __half2*)&Hg[((size_t)wid << 5) + 2 * c16]);
            a0 += ws * f.x; a1 += ws * f.y;
        }
    }

    auto g64 = [&](int j, auto NEhalf) {  // M loads/lane, 2M edges
        constexpr int M = decltype(NEhalf)::value;
        float2 hv[M]; float wv[M];
        #pragma unroll
        for (int u = 0; u < M; ++u) {
            int2 p = sw[wvi][j + 2 * u + sub];
            wv[u] = __int_as_float(p.y);
            hv[u] = __half22float2(*(const __half2*)&Hg[((size_t)p.x << 6) + 2 * c32]);
        }
        #pragma unroll
        for (int u = 0; u < M; ++u) {
            if (u & 1) { b0 += wv[u] * hv[u].x; b1 += wv[u] * hv[u].y; }
            else       { a0 += wv[u] * hv[u].x; a1 += wv[u] * hv[u].y; }
        }
    };
    auto g32 = [&](int j, auto NEq) {  // M loads/lane, 4M edges
        constexpr int M = decltype(NEq)::value;
        float2 hv[M]; float wv[M];
        #pragma unroll
        for (int u = 0; u < M; ++u) {
            int2 p = sw[wvi][j + 4 * u + quad];
            wv[u] = __int_as_float(p.y);
            hv[u] = __half22float2(*(const __half2*)&Hg[((size_t)p.x << 5) + 2 * c16]);
        }
        #pragma unroll
        for (int u = 0; u < M; ++u) {
            if (u & 1) { b0 += wv[u] * hv[u].x; b1 += wv[u] * hv[u].y; }
            else       { a0 += wv[u] * hv[u].x; a1 += wv[u] * hv[u].y; }
        }
    };

    if (C == 64) {
        if (dg <= 8)       g64(0, std::integral_constant<int, 4>{});
        else if (dg <= 16) g64(0, std::integral_constant<int, 8>{});
        else if (dg <= 32) g64(0, std::integral_constant<int, 16>{});
        else { g64(0, std::integral_constant<int, 16>{}); g64(32, std::integral_constant<int, 16>{}); }
    } else {
        if (dg <= 16)      g32(0, std::integral_constant<int, 4>{});
        else if (dg <= 32) g32(0, std::integral_constant<int, 8>{});
        else { g32(0, std::integral_constant<int, 8>{}); g32(32, std::integral_constant<int, 8>{}); }
    }

    float f0 = a0 + b0, f1 = a1 + b1;
    if (C == 32) { f0 += __shfl_xor(f0, 16); f1 += __shfl_xor(f1, 16); }
    f0 += __shfl_xor(f0, 32); f1 += __shfl_xor(f1, 32);
    #pragma unroll
    for (int off = 32; off; off >>= 1) denom += __shfl_xor(denom, off);

    float inv = 1.f / denom;
    float v0 = f0 * inv, v1 = f1 * inv;

    if (MODE == 0) {
        if (!sub) {
            __half2 p = __floats2half2_rn(v0, v1);
            *(__half2*)&outh[((size_t)wid << 6) + 2 * c32] = p;
        }
    } else if (MODE == 1) {
        float2 bb = *(const float2*)&bias[2 * c32];
        v0 += bb.x; v1 += bb.y;
        v0 = v0 > 0.f ? v0 : 0.01f * v0;
        v1 = v1 > 0.f ? v1 : 0.01f * v1;
        if (!sub) {
            __half2 p = __floats2half2_rn(v0, v1);
            *(__half2*)&outh[((size_t)wid << 6) + 2 * c32] = p;
        }
        float2 wsv = *(const float2*)&was[2 * c32];
        float2 wdv = *(const float2*)&wad[2 * c32];
        float s1 = v0 * wsv.x + v1 * wsv.y;
        float s2 = v0 * wdv.x + v1 * wdv.y;
        #pragma unroll
        for (int off = 16; off; off >>= 1) {
            s1 += __shfl_xor(s1, off);
            s2 += __shfl_xor(s2, off);
        }
        if (lane == 0) { oas[wid] = s1; oad[wid] = s2; }
    } else {
        if (!quad) {
            float2 bb = *(const float2*)&bias[2 * c16];
            float2 o = {v0 + bb.x, v1 + bb.y};
            *(float2*)&outf[((size_t)wid << 5) + 2 * c16] = o;
        }
    }
}

// ---------------- launch ----------------

extern "C" void kernel_launch(void* const* d_in, const int* in_sizes, int n_in,
                              void* d_out, int out_size, void* d_ws, size_t ws_size,
                              hipStream_t stream) {
    const float* x  = (const float*)d_in[0];
    const int* ei   = (const int*)d_in[1];
    const float* W1 = (const float*)d_in[2];
    const float* a1s = (const float*)d_in[3];
    const float* a1d = (const float*)d_in[4];
    const float* b1  = (const float*)d_in[5];
    const float* W2 = (const float*)d_in[6];
    const float* a2s = (const float*)d_in[7];
    const float* a2d = (const float*)d_in[8];
    const float* b2  = (const float*)d_in[9];
    const float* W3 = (const float*)d_in[10];
    const float* a3s = (const float*)d_in[11];
    const float* a3d = (const float*)d_in[12];
    const float* b3  = (const float*)d_in[13];
    const float* W4 = (const float*)d_in[14];
    const float* a4s = (const float*)d_in[15];
    const float* a4d = (const float*)d_in[16];
    const float* b4  = (const float*)d_in[17];

    const int N = in_sizes[0] / 64;     // 50000
    const int E = in_sizes[1] / 2;      // 800000
    const int* src = ei;
    const int* dst = ei + E;

    // workspace layout (16B-aligned segments for N=50000)
    float* asA  = (float*)d_ws;             // N
    float* adA  = asA + N;                  // N
    float* asB  = adA + N;                  // N
    float* adB  = asB + N;                  // N
    float* wa   = adB + N;                  // 256 (4x64)
    int* cnt    = (int*)(wa + 256);         // N (degree after scatter)
    unsigned short* col = (unsigned short*)(cnt + N);  // N*64 ushort padded CSR
    __half* x16 = (__half*)(col + (size_t)N * 64);     // N*64 fp16
    __half* g1  = x16 + (size_t)N * 64;     // N*64 fp16 (H2 / H4)
    __half* g2  = g1 + (size_t)N * 64;      // N*64 fp16 (O2)
    __half* g3  = g2 + (size_t)N * 64;      // N*64 fp16 (T1/T3)
    __half* g4  = g3 + (size_t)N * 64;      // N*128 fp16 (H1/H3)

    const int NB = (N + 255) / 256;         // 196
    const int STEP = (N + 7) / 8;
    const int SB = 2048;
    const int ITERS4 = ((E >> 2) + (SB / 8) * 256 - 1) / ((SB / 8) * 256);  // 4
    const int NWAVE = (N * 64 + 255) / 256; // 12500

    // ---- setup: zero cnt + wa vectors ----
    setup_k<<<NB + 1, 256, 0, stream>>>(cnt, N, NB, W1, a1s, a1d, W3, a3s, a3d, wa);
    float* wa1s = wa, *wa1d = wa + 64, *wa3s = wa + 128, *wa3d = wa + 192;

    // ---- XCD-local partitioned scatter + layer-1 gemv + x16 ----
    scatter_gemv_k<<<SB + NWAVE, 256, 0, stream>>>(src, dst, cnt, col, E, STEP, SB, ITERS4,
                                                   x, wa1s, wa1d, asA, adA, x16, N);

    // ---- layer 1 (aggregate-first): T1(fp16) = Ahat @ x ; H1(fp16) = leaky(T1@W1 + b1) ----
    agg_k<64, 0><<<NWAVE, 256, 0, stream>>>(x16, asA, adA, cnt, col, nullptr, nullptr, nullptr,
                                            nullptr, g3, nullptr, nullptr, N);
    gemm_wide_k<<<(N + 127) / 128, 256, 0, stream>>>(g3, W1, b1, g4, N);

    // ---- layer 2: H2(fp16) = H1 @ W2 (+logits2) ; O2(fp16) = leaky(Ahat@H2+b2) (+logits3) ----
    gemm_k<128, 64><<<(N + 31) / 32, 256, 0, stream>>>(g4, W2, a2s, a2d, g1, asB, adB, N);
    agg_k<64, 1><<<NWAVE, 256, 0, stream>>>(g1, asB, adB, cnt, col, b2, wa3s, wa3d,
                                            nullptr, g2, asA, adA, N);

    // ---- layer 3 (aggregate-first): T3(fp16) = Ahat @ O2 ; H3(fp16) = leaky(T3@W3 + b3) ----
    agg_k<64, 0><<<NWAVE, 256, 0, stream>>>(g2, asA, adA, cnt, col, nullptr, nullptr, nullptr,
                                            nullptr, g3, nullptr, nullptr, N);
    gemm_wide_k<<<(N + 127) / 128, 256, 0, stream>>>(g3, W3, b3, g4, N);

    // ---- layer 4: H4(fp16) = H3 @ W4 (+logits4) ; out = Ahat@H4 + b4 ----
    gemm_k<128, 32><<<(N + 63) / 64, 256, 0, stream>>>(g4, W4, a4s, a4d, g1, asB, adB, N);
    agg_k<32, 2><<<NWAVE, 256, 0, stream>>>(g1, asB, adB, cnt, col, b4, nullptr, nullptr,
                                            (float*)d_out, nullptr, nullptr, nullptr, N);
}